// Round 10
// baseline (295.557 us; speedup 1.0000x reference)
//
#include <hip/hip_runtime.h>

// ---------------------------------------------------------------------------
// GridNet fused forward: MLP (bf16 MFMA) + softmax + 5x5 gather + sigmoid
// B=262144, GS=(1024,2048), NS=5, layers 2-64-256-512-256-64-75
// Model (fits R5..R13): per-k-iter serial chain ~200-240cyc regardless of
//   schedule; MfmaUtil = per-wave duty x waves/SIMD. R13 (212us steady) got
//   duty 16.5% (pinned A-preload, 4 MFMA/iter) but only 2 waves/SIMD
//   (M=128 -> 154.6KB LDS -> 1 blk/CU). R5 had 4 waves/SIMD but duty 7%.
// R14: BOTH levers: R13 per-wave machinery at M=64 / 77.3KB LDS / 2 blk/CU
//   (4 waves/SIMD). 32-shape: NT=2, OG=8, PTG=1 (weights read once/wave).
//   PRE=8 pinned A-batches (64 VGPR); L3b PRE=2 (acc3+acc4 live).
//   launch_bounds(512,4) -> 128 VGPR cap; budget ~112-127.
//   Keeps: cvt_pk stores, setprio MFMA clusters, early epilogue gathers.
// ---------------------------------------------------------------------------

#define PI_F     3.14159265358979323846f
#define TWO_PI_F 6.28318530717958647692f

typedef __attribute__((ext_vector_type(8))) short bf16x8;   // 8 bf16 = 4 VGPRs
typedef __attribute__((ext_vector_type(4))) short bf16x4;   // 8 B packed
typedef __attribute__((ext_vector_type(4))) float f32x4;    // 16x16 MFMA C/D
typedef __attribute__((ext_vector_type(16))) float f32x16;  // 32x32 MFMA C/D
typedef __attribute__((ext_vector_type(4))) __bf16 bfv4;

__device__ __forceinline__ short f2bf(float f) {            // RNE, 1 instr
    __bf16 b = (__bf16)f;
    return __builtin_bit_cast(short, b);
}
__device__ __forceinline__ bf16x4 cvt4(f32x4 v) {           // 2x v_cvt_pk_bf16_f32
    bfv4 b = __builtin_convertvector(v, bfv4);
    return __builtin_bit_cast(bf16x4, b);
}

// ws layout (shorts). Weights fragment-packed for MFMA A-operand.
// 16-shape layers (L2,L5,L6): frag f = ot*KT + kt (ot 16-wide, kt 32-deep):
//   lane*8+e <-> W[k = kt*32 + (lane>>4)*8 + e][n = ot*16 + (lane&15)]
// 32-shape layers (L3,L4):    frag f = ot*KT + kt (ot 32-wide, kt 16-deep):
//   lane*8+e <-> W[k = kt*16 + (lane>>5)*8 + e][n = ot*32 + (lane&31)]
// L2: 64x256 (KT=2,  16-shape) @ 0       (16384)
// L3: 256x512(KT=16, 32-shape) @ 16384   (131072)
// L4: 512x256(KT=32, 32-shape) @ 147456  (131072)
// L5: 256x64 (KT=8,  16-shape) @ 278528  (16384)
// L6: 64x80  (KT=2,  16-shape) @ 294912  (5120, cols 75..79 zeroed)
// b6pad: 80 f32 @ short-offset 300032
#define P2_OFF 0
#define P3_OFF 16384
#define P4_OFF 147456
#define P5_OFF 278528
#define P6_OFF 294912
#define B6_OFF 300032
#define PREP_W_TOTAL 300032
#define PREP_TOTAL (PREP_W_TOTAL + 80)

__global__ void prep_weights(const float* __restrict__ w2, const float* __restrict__ w3,
                             const float* __restrict__ w4, const float* __restrict__ w5,
                             const float* __restrict__ w6, const float* __restrict__ b6,
                             short* __restrict__ ws) {
    int idx = blockIdx.x * blockDim.x + threadIdx.x;
    if (idx >= PREP_TOTAL) return;
    if (idx >= PREP_W_TOTAL) {                   // padded bias6 as float
        int n = idx - PREP_W_TOTAL;
        ((float*)(ws + B6_OFF))[n] = (n < 75) ? b6[n] : 0.0f;
        return;
    }
    int rel, KT, N;
    bool s32;
    const float* W;
    if (idx < P3_OFF)      { rel = idx - P2_OFF; KT = 2;  N = 256; W = w2; s32 = false; }
    else if (idx < P4_OFF) { rel = idx - P3_OFF; KT = 16; N = 512; W = w3; s32 = true;  }
    else if (idx < P5_OFF) { rel = idx - P4_OFF; KT = 32; N = 256; W = w4; s32 = true;  }
    else if (idx < P6_OFF) { rel = idx - P5_OFF; KT = 8;  N = 64;  W = w5; s32 = false; }
    else                   { rel = idx - P6_OFF; KT = 2;  N = 80;  W = w6; s32 = false; }
    int f = rel >> 9, r = rel & 511, lane = r >> 3, e = r & 7;
    int kt = f % KT, ot = f / KT;
    int n, k;
    if (s32) { n = ot * 32 + (lane & 31); k = kt * 16 + (lane >> 5) * 8 + e; }
    else     { n = ot * 16 + (lane & 15); k = kt * 32 + (lane >> 4) * 8 + e; }
    float v;
    if (N == 80) v = (n < 75) ? w6[k * 75 + n] : 0.0f;   // true row stride 75
    else         v = W[k * N + n];
    ws[idx] = f2bf(v);
}

// ---- 16x16x32 role-swapped layer (L2, L5, L6), full A-preload -------------
// D[od][pt] = sum_k W^T[od][k] * act[k][pt] (+bias[od])
// PTS: 16-pt tiles in block (M/16). PTG = PTS/NT; OG = ODT/MT.
template<int K, int ODT, int PTS, int MT, int NT, int KTS, int KT0,
         bool RELU, bool OUTF32, bool INIT, bool STORE>
__device__ __forceinline__ void mlp_layer(f32x4 (&acc)[MT][NT],
                                          const short* __restrict__ act, const int sIn,
                                          void* __restrict__ outP, const int sOut,
                                          const short* __restrict__ pack,
                                          const float* __restrict__ bias,
                                          const int wave, const int lane) {
    constexpr int PTG = PTS / NT;        // point groups
    constexpr int OG  = ODT / MT;        // od groups
    constexpr int KT  = K / 32;          // k-tiles this pass
    const int og = wave / PTG;
    if (og >= OG) return;
    const int ptb = (wave % PTG) * (NT * 16);
    const int otb = og * MT;
    const int lr = lane & 15, lq = lane >> 4;

    const short* ap = pack + ((otb * KTS + KT0) << 9) + (lane << 3);
    const short* bp = act + (ptb + lr) * sIn + lq * 8;

    if (INIT) {                          // bias first: counted wait, no drain
        #pragma unroll
        for (int i = 0; i < MT; ++i) {
            f32x4 bv = *(const f32x4*)(bias + (otb + i) * 16 + lq * 4);
            #pragma unroll
            for (int j = 0; j < NT; ++j) acc[i][j] = bv;
        }
    }

    // batch-issue ALL A-frags; pin so the compiler can't sink them
    bf16x8 a[KT][MT];
    #pragma unroll
    for (int kt = 0; kt < KT; ++kt) {
        #pragma unroll
        for (int i = 0; i < MT; ++i)
            a[kt][i] = *(const bf16x8*)(ap + ((i * KTS + kt) << 9));
    }
    __builtin_amdgcn_sched_barrier(0);

    bf16x8 b[2][NT];
    #pragma unroll
    for (int j = 0; j < NT; ++j) b[0][j] = *(const bf16x8*)(bp + j * 16 * sIn);

    #pragma unroll
    for (int kt = 0; kt < KT; ++kt) {
        if (kt + 1 < KT) {
            #pragma unroll
            for (int j = 0; j < NT; ++j)
                b[(kt + 1) & 1][j] = *(const bf16x8*)(bp + j * 16 * sIn + (kt + 1) * 32);
        }
        __builtin_amdgcn_s_setprio(1);
        #pragma unroll
        for (int i = 0; i < MT; ++i) {
            #pragma unroll
            for (int j = 0; j < NT; ++j)
                acc[i][j] = __builtin_amdgcn_mfma_f32_16x16x32_bf16(a[kt][i], b[kt & 1][j], acc[i][j], 0, 0, 0);
        }
        __builtin_amdgcn_s_setprio(0);
    }

    if (STORE) {
        #pragma unroll
        for (int i = 0; i < MT; ++i) {
            #pragma unroll
            for (int j = 0; j < NT; ++j) {
                const int row = ptb + j * 16 + lr;          // point
                const int col = (otb + i) * 16 + lq * 4;    // output dim (4 contiguous)
                if (OUTF32) {
                    *(f32x4*)((float*)outP + row * sOut + col) = acc[i][j];
                } else {
                    f32x4 v = acc[i][j];
                    if (RELU) {
                        v[0] = fmaxf(v[0], 0.0f); v[1] = fmaxf(v[1], 0.0f);
                        v[2] = fmaxf(v[2], 0.0f); v[3] = fmaxf(v[3], 0.0f);
                    }
                    *(bf16x4*)((short*)outP + row * sOut + col) = cvt4(v);
                }
            }
        }
    }
}

// ---- 32x32x16 batched-preload role-swapped layer (L3, L4) -----------------
//  A: lane -> A[od = otb*32 + (lane&31)][k = kt*16 + (lane>>5)*8 + e]
//  B: lane -> act[pt = ptb + (lane&31)][k = kt*16 + (lane>>5)*8 + e]
//  D (m74/m101): pt = lane&31, od = (r&3) + 8*(r>>2) + 4*(lane>>5)
// PRE: A-frags per batch (2-deep batches issued one ahead, pinned).
template<int K, int OT, int PTS, int MT, int NT, int KTS, int KT0, int PRE,
         bool RELU, bool INIT, bool STORE>
__device__ __forceinline__ void mlp_layer32p(f32x16 (&acc)[MT][NT],
                                             const short* __restrict__ act, const int sIn,
                                             short* __restrict__ outP, const int sOut,
                                             const short* __restrict__ pack,
                                             const float* __restrict__ bias,
                                             const int wave, const int lane) {
    constexpr int PTG = PTS / NT;
    constexpr int OG  = OT / MT;
    constexpr int KT  = K / 16;
    constexpr int NB  = KT / PRE;        // batches (KT % PRE == 0)
    constexpr int AB  = (NB > 1) ? 2 : 1;
    const int og = wave / PTG;
    if (og >= OG) return;
    const int ptb = (wave % PTG) * (NT * 32);
    const int otb = og * MT;
    const int lr = lane & 31, hi = lane >> 5;

    const short* ap = pack + ((otb * KTS + KT0) << 9) + (lane << 3);
    const short* bp = act + (ptb + lr) * sIn + hi * 8;

    if (INIT) {                          // bias first: counted wait, no drain
        #pragma unroll
        for (int i = 0; i < MT; ++i) {
            #pragma unroll
            for (int rg = 0; rg < 4; ++rg) {
                f32x4 bv = *(const f32x4*)(bias + (otb + i) * 32 + rg * 8 + hi * 4);
                #pragma unroll
                for (int j = 0; j < NT; ++j) {
                    acc[i][j][rg * 4 + 0] = bv[0];
                    acc[i][j][rg * 4 + 1] = bv[1];
                    acc[i][j][rg * 4 + 2] = bv[2];
                    acc[i][j][rg * 4 + 3] = bv[3];
                }
            }
        }
    }

    bf16x8 a[AB][PRE][MT], b[2][NT];

#define LOADA(B_, C_)                                                           \
    {   _Pragma("unroll")                                                       \
        for (int t = 0; t < PRE; ++t) {                                         \
            _Pragma("unroll")                                                   \
            for (int i = 0; i < MT; ++i)                                        \
                a[B_][t][i] = *(const bf16x8*)(ap + ((i * KTS + (C_) * PRE + t) << 9)); \
        }                                                                       \
        __builtin_amdgcn_sched_barrier(0); }

    LOADA(0, 0)
    #pragma unroll
    for (int j = 0; j < NT; ++j) b[0][j] = *(const bf16x8*)(bp + j * 32 * sIn);

    #pragma unroll
    for (int bb = 0; bb < NB; ++bb) {
        if (bb + 1 < NB) LOADA((bb + 1) % AB, bb + 1)
        #pragma unroll
        for (int t = 0; t < PRE; ++t) {
            const int kt = bb * PRE + t;
            if (kt + 1 < KT) {
                #pragma unroll
                for (int j = 0; j < NT; ++j)
                    b[(kt + 1) & 1][j] = *(const bf16x8*)(bp + j * 32 * sIn + (kt + 1) * 16);
            }
            __builtin_amdgcn_s_setprio(1);
            #pragma unroll
            for (int i = 0; i < MT; ++i) {
                #pragma unroll
                for (int j = 0; j < NT; ++j)
                    acc[i][j] = __builtin_amdgcn_mfma_f32_32x32x16_bf16(
                        a[bb % AB][t][i], b[kt & 1][j], acc[i][j], 0, 0, 0);
            }
            __builtin_amdgcn_s_setprio(0);
        }
    }
#undef LOADA

    if (STORE) {
        #pragma unroll
        for (int i = 0; i < MT; ++i) {
            #pragma unroll
            for (int j = 0; j < NT; ++j) {
                const int row = ptb + j * 32 + lr;
                #pragma unroll
                for (int rg = 0; rg < 4; ++rg) {
                    f32x4 v;
                    v[0] = acc[i][j][rg * 4 + 0]; v[1] = acc[i][j][rg * 4 + 1];
                    v[2] = acc[i][j][rg * 4 + 2]; v[3] = acc[i][j][rg * 4 + 3];
                    if (RELU) {
                        v[0] = fmaxf(v[0], 0.0f); v[1] = fmaxf(v[1], 0.0f);
                        v[2] = fmaxf(v[2], 0.0f); v[3] = fmaxf(v[3], 0.0f);
                    }
                    *(bf16x4*)(outP + row * sOut + (otb + i) * 32 + rg * 8 + hi * 4) = cvt4(v);
                }
            }
        }
    }
}

__global__ __launch_bounds__(512, 4) void gridnet_fused(
    const float* __restrict__ pos, const float* __restrict__ grid_pos,
    const float* __restrict__ w1, const float* __restrict__ b1,
    const float* __restrict__ b2, const float* __restrict__ b3,
    const float* __restrict__ b4, const float* __restrict__ b5,
    const short* __restrict__ ws, float* __restrict__ out) {

    // M=64 pts/block. region1: h2 -> h4.  region2: h3a/h3b -> logits(f32).
    // region3: h1 -> h5.  Peak LDS = 33792+33792+9216+512 = 77312 B -> 2 blk/CU.
    __shared__ short region1[64 * 264];
    __shared__ short region2[64 * 264];
    __shared__ short region3[64 * 72];
    __shared__ float posS[128];
    float* logitsS = (float*)region2;    // 64*80*4 = 20480 <= 33792

    const int tid  = threadIdx.x;
    const int wave = tid >> 6;
    const int lane = tid & 63;
    const int m0   = blockIdx.x * 64;

    // ---- early-issue epilogue gathers (depend only on pos); ~10 VGPR ------
    const int pe = tid >> 3;             // point within tile
    const int se = tid & 7;              // sub-lane
    const float pa0 = pos[(m0 + pe) * 2], pa1 = pos[(m0 + pe) * 2 + 1];
    const int txa = (int)(pa0 / PI_F * 1023.0f);
    const int tya = (int)((pa1 + PI_F) / TWO_PI_F * 2047.0f);
    float g0[10];
    #pragma unroll
    for (int i = 0; i < 10; ++i) {
        int f = se + i * 8;
        if (f < 75) {
            int c = f / 25, rr = f % 25, dy = rr / 5, dx = rr % 5;
            g0[i] = grid_pos[((txa + dy) * 2052 + (tya + dx)) * 3 + c];
        } else g0[i] = 0.0f;
    }

    if (tid < 128) posS[tid] = pos[m0 * 2 + tid];
    __syncthreads();

    // ---- layer 1 (2 -> 64), VALU; h1 stored [pt][dim] stride 72 ----
    #pragma unroll
    for (int r = 0; r < 8; ++r) {
        int idx = tid + r * 512;          // 64 pts x 64 dims
        int m = idx >> 6, n = idx & 63;
        float v = fmaf(posS[m * 2 + 0], w1[n], fmaf(posS[m * 2 + 1], w1[64 + n], b1[n]));
        region3[m * 72 + n] = f2bf(fmaxf(v, 0.0f));
    }
    __syncthreads();

    {   // L2: 64 -> 256. PTS=4, NT=4 (PTG=1), MT=2 (OG=8). A preload 16 VGPR.
        f32x4 acc[2][4];
        mlp_layer< 64, 16, 4, 2, 4,  2, 0, true, false, true, true>(
            acc, region3, 72, region1, 264, ws + P2_OFF, b2, wave, lane);
    }
    __syncthreads();

    {   // L3/L4 halves; PTG=1 on 32-shape (NT=2): each weight frag read by
        // ONE wave; its B spans all 64 pts. OG=8, MT=1.
        f32x16 acc4[1][2];
        {   // L3a: h2 -> h3a (od 0..255). PRE=8 (A dbuf 64 VGPR).
            f32x16 acc[1][2];
            mlp_layer32p<256, 8, 2, 1, 2, 16, 0, 8, true, true, true>(
                acc, region1, 264, region2, 264, ws + P3_OFF, b3, wave, lane);
        }
        __syncthreads();
        // L4 part 1: k = 0..255 (h3a), bias-init, no store. PRE=8.
        mlp_layer32p<256, 8, 2, 1, 2, 32, 0, 8, true, true, false>(
            acc4, region2, 264, region1, 264, ws + P4_OFF, b4, wave, lane);
        __syncthreads();
        {   // L3b: h2 -> h3b (od 256..511); PRE=2 (acc3+acc4 live, VGPR cap 128)
            f32x16 acc[1][2];
            mlp_layer32p<256, 8, 2, 1, 2, 16, 0, 2, true, true, true>(
                acc, region1, 264, region2, 264, ws + P3_OFF + 65536, b3 + 256,
                wave, lane);
        }
        __syncthreads();
        // L4 part 2: k = 256..511 (weight k-tiles 16..31), store h4. PRE=8.
        mlp_layer32p<256, 8, 2, 1, 2, 32, 16, 8, true, false, true>(
            acc4, region2, 264, region1, 264, ws + P4_OFF, b4, wave, lane);
    }
    __syncthreads();

    {   // L5: 256 -> 64. PTS=4, NT=2 (PTG=2), MT=1 (OG=4). A preload 32 VGPR.
        f32x4 acc[1][2];
        mlp_layer<256,  4, 4, 1, 2,  8, 0, true, false, true, true>(
            acc, region1, 264, region3, 72, ws + P5_OFF, b5, wave, lane);
    }
    __syncthreads();

    {   // L6: 64 -> 80 logits (f32). PTS=4, NT=4 (PTG=1), MT=1, OG=5.
        f32x4 acc[1][4];
        mlp_layer< 64,  5, 4, 1, 4,  2, 0, false, true, true, true>(
            acc, region3, 72, logitsS, 80, ws + P6_OFF,
            (const float*)(ws + B6_OFF), wave, lane);
    }
    __syncthreads();

    // ---- epilogue: softmax(75) + preloaded gather + sigmoid ----
    {
        const float* lrow = logitsS + pe * 80;
        float lv[10];
        float mx = -1e30f;
        #pragma unroll
        for (int i = 0; i < 10; ++i) {
            int f = se + i * 8;
            float v = (f < 75) ? lrow[f] : -1e30f;
            lv[i] = v;
            mx = fmaxf(mx, v);
        }
        mx = fmaxf(mx, __shfl_xor(mx, 1, 8));
        mx = fmaxf(mx, __shfl_xor(mx, 2, 8));
        mx = fmaxf(mx, __shfl_xor(mx, 4, 8));

        float den = 0.0f, x0 = 0.0f, x1 = 0.0f, x2 = 0.0f;
        #pragma unroll
        for (int i = 0; i < 10; ++i) {
            int f = se + i * 8;
            if (f < 75) {
                float e = __expf(lv[i] - mx);
                den += e;
                int c = f / 25;
                if      (c == 0) x0 += e * g0[i];
                else if (c == 1) x1 += e * g0[i];
                else             x2 += e * g0[i];
            }
        }
        #pragma unroll
        for (int mask = 1; mask < 8; mask <<= 1) {
            den += __shfl_xor(den, mask, 8);
            x0  += __shfl_xor(x0,  mask, 8);
            x1  += __shfl_xor(x1,  mask, 8);
            x2  += __shfl_xor(x2,  mask, 8);
        }
        if (se < 3) {
            float xv = (se == 0) ? x0 : (se == 1 ? x1 : x2);
            xv /= den;
            float sig = 1.0f / (1.0f + __expf(-xv));
            out[(m0 + pe) * 3 + se] = (sig > 0.1f) ? sig * 255.0f : 0.0f;
        }
    }
}

extern "C" void kernel_launch(void* const* d_in, const int* in_sizes, int n_in,
                              void* d_out, int out_size, void* d_ws, size_t ws_size,
                              hipStream_t stream) {
    const float* pos      = (const float*)d_in[0];
    const float* grid_pos = (const float*)d_in[1];
    const float* w1 = (const float*)d_in[2];
    const float* b1 = (const float*)d_in[3];
    const float* w2 = (const float*)d_in[4];
    const float* b2 = (const float*)d_in[5];
    const float* w3 = (const float*)d_in[6];
    const float* b3 = (const float*)d_in[7];
    const float* w4 = (const float*)d_in[8];
    const float* b4 = (const float*)d_in[9];
    const float* w5 = (const float*)d_in[10];
    const float* b5 = (const float*)d_in[11];
    const float* w6 = (const float*)d_in[12];
    const float* b6 = (const float*)d_in[13];
    short* ws = (short*)d_ws;
    float* out = (float*)d_out;

    prep_weights<<<(PREP_TOTAL + 255) / 256, 256, 0, stream>>>(w2, w3, w4, w5, w6, b6, ws);
    gridnet_fused<<<262144 / 64, 512, 0, stream>>>(pos, grid_pos, w1, b1, b2, b3, b4, b5, ws, out);
}

// Round 11
// 264.271 us; speedup vs baseline: 1.1184x; 1.1184x over previous
//
#include <hip/hip_runtime.h>

// ---------------------------------------------------------------------------
// GridNet fused forward: MLP (bf16 MFMA) + softmax + 5x5 gather + sigmoid
// B=262144, GS=(1024,2048), NS=5, layers 2-64-256-512-256-64-75
// Model (fits R5..R14): MfmaUtil = per-wave duty x waves/SIMD; duty needs
//   pinned deep A-preload (R13: 16.5% duty, 212us steady @ 2 waves/SIMD).
// R14 = R13 machinery @ M=64 / 2 blk/CU FAILED mechanically: allocator
//   clamped VGPR to 64 (chasing 8 waves/EU that LDS already forbids) and
//   SPILLED: WRITE_SIZE 3MB -> 109.6MB, dur 234us.
// R15: force the allocator: amdgpu_waves_per_eu(4,4) => no benefit below
//   128 VGPR => use the budget. PRE 8->4 (A-dbuf 32 VGPR) so worst point
//   (L3b: acc3 32 + acc4 32 + A 16 + b 16 + g0 10 + addr) fits ~120 <= 128.
//   Else identical to R14. Verify: WRITE_SIZE back to ~3MB, VGPR 100-128.
// ---------------------------------------------------------------------------

#define PI_F     3.14159265358979323846f
#define TWO_PI_F 6.28318530717958647692f

typedef __attribute__((ext_vector_type(8))) short bf16x8;   // 8 bf16 = 4 VGPRs
typedef __attribute__((ext_vector_type(4))) short bf16x4;   // 8 B packed
typedef __attribute__((ext_vector_type(4))) float f32x4;    // 16x16 MFMA C/D
typedef __attribute__((ext_vector_type(16))) float f32x16;  // 32x32 MFMA C/D
typedef __attribute__((ext_vector_type(4))) __bf16 bfv4;

__device__ __forceinline__ short f2bf(float f) {            // RNE, 1 instr
    __bf16 b = (__bf16)f;
    return __builtin_bit_cast(short, b);
}
__device__ __forceinline__ bf16x4 cvt4(f32x4 v) {           // 2x v_cvt_pk_bf16_f32
    bfv4 b = __builtin_convertvector(v, bfv4);
    return __builtin_bit_cast(bf16x4, b);
}

// ws layout (shorts). Weights fragment-packed for MFMA A-operand.
// 16-shape layers (L2,L5,L6): frag f = ot*KT + kt (ot 16-wide, kt 32-deep):
//   lane*8+e <-> W[k = kt*32 + (lane>>4)*8 + e][n = ot*16 + (lane&15)]
// 32-shape layers (L3,L4):    frag f = ot*KT + kt (ot 32-wide, kt 16-deep):
//   lane*8+e <-> W[k = kt*16 + (lane>>5)*8 + e][n = ot*32 + (lane&31)]
// L2: 64x256 (KT=2,  16-shape) @ 0       (16384)
// L3: 256x512(KT=16, 32-shape) @ 16384   (131072)
// L4: 512x256(KT=32, 32-shape) @ 147456  (131072)
// L5: 256x64 (KT=8,  16-shape) @ 278528  (16384)
// L6: 64x80  (KT=2,  16-shape) @ 294912  (5120, cols 75..79 zeroed)
// b6pad: 80 f32 @ short-offset 300032
#define P2_OFF 0
#define P3_OFF 16384
#define P4_OFF 147456
#define P5_OFF 278528
#define P6_OFF 294912
#define B6_OFF 300032
#define PREP_W_TOTAL 300032
#define PREP_TOTAL (PREP_W_TOTAL + 80)

__global__ void prep_weights(const float* __restrict__ w2, const float* __restrict__ w3,
                             const float* __restrict__ w4, const float* __restrict__ w5,
                             const float* __restrict__ w6, const float* __restrict__ b6,
                             short* __restrict__ ws) {
    int idx = blockIdx.x * blockDim.x + threadIdx.x;
    if (idx >= PREP_TOTAL) return;
    if (idx >= PREP_W_TOTAL) {                   // padded bias6 as float
        int n = idx - PREP_W_TOTAL;
        ((float*)(ws + B6_OFF))[n] = (n < 75) ? b6[n] : 0.0f;
        return;
    }
    int rel, KT, N;
    bool s32;
    const float* W;
    if (idx < P3_OFF)      { rel = idx - P2_OFF; KT = 2;  N = 256; W = w2; s32 = false; }
    else if (idx < P4_OFF) { rel = idx - P3_OFF; KT = 16; N = 512; W = w3; s32 = true;  }
    else if (idx < P5_OFF) { rel = idx - P4_OFF; KT = 32; N = 256; W = w4; s32 = true;  }
    else if (idx < P6_OFF) { rel = idx - P5_OFF; KT = 8;  N = 64;  W = w5; s32 = false; }
    else                   { rel = idx - P6_OFF; KT = 2;  N = 80;  W = w6; s32 = false; }
    int f = rel >> 9, r = rel & 511, lane = r >> 3, e = r & 7;
    int kt = f % KT, ot = f / KT;
    int n, k;
    if (s32) { n = ot * 32 + (lane & 31); k = kt * 16 + (lane >> 5) * 8 + e; }
    else     { n = ot * 16 + (lane & 15); k = kt * 32 + (lane >> 4) * 8 + e; }
    float v;
    if (N == 80) v = (n < 75) ? w6[k * 75 + n] : 0.0f;   // true row stride 75
    else         v = W[k * N + n];
    ws[idx] = f2bf(v);
}

// ---- 16x16x32 role-swapped layer (L2, L5, L6), full A-preload -------------
// D[od][pt] = sum_k W^T[od][k] * act[k][pt] (+bias[od])
// PTS: 16-pt tiles in block (M/16). PTG = PTS/NT; OG = ODT/MT.
template<int K, int ODT, int PTS, int MT, int NT, int KTS, int KT0,
         bool RELU, bool OUTF32, bool INIT, bool STORE>
__device__ __forceinline__ void mlp_layer(f32x4 (&acc)[MT][NT],
                                          const short* __restrict__ act, const int sIn,
                                          void* __restrict__ outP, const int sOut,
                                          const short* __restrict__ pack,
                                          const float* __restrict__ bias,
                                          const int wave, const int lane) {
    constexpr int PTG = PTS / NT;        // point groups
    constexpr int OG  = ODT / MT;        // od groups
    constexpr int KT  = K / 32;          // k-tiles this pass
    const int og = wave / PTG;
    if (og >= OG) return;
    const int ptb = (wave % PTG) * (NT * 16);
    const int otb = og * MT;
    const int lr = lane & 15, lq = lane >> 4;

    const short* ap = pack + ((otb * KTS + KT0) << 9) + (lane << 3);
    const short* bp = act + (ptb + lr) * sIn + lq * 8;

    if (INIT) {                          // bias first: counted wait, no drain
        #pragma unroll
        for (int i = 0; i < MT; ++i) {
            f32x4 bv = *(const f32x4*)(bias + (otb + i) * 16 + lq * 4);
            #pragma unroll
            for (int j = 0; j < NT; ++j) acc[i][j] = bv;
        }
    }

    // batch-issue ALL A-frags; pin so the compiler can't sink them
    bf16x8 a[KT][MT];
    #pragma unroll
    for (int kt = 0; kt < KT; ++kt) {
        #pragma unroll
        for (int i = 0; i < MT; ++i)
            a[kt][i] = *(const bf16x8*)(ap + ((i * KTS + kt) << 9));
    }
    __builtin_amdgcn_sched_barrier(0);

    bf16x8 b[2][NT];
    #pragma unroll
    for (int j = 0; j < NT; ++j) b[0][j] = *(const bf16x8*)(bp + j * 16 * sIn);

    #pragma unroll
    for (int kt = 0; kt < KT; ++kt) {
        if (kt + 1 < KT) {
            #pragma unroll
            for (int j = 0; j < NT; ++j)
                b[(kt + 1) & 1][j] = *(const bf16x8*)(bp + j * 16 * sIn + (kt + 1) * 32);
        }
        __builtin_amdgcn_s_setprio(1);
        #pragma unroll
        for (int i = 0; i < MT; ++i) {
            #pragma unroll
            for (int j = 0; j < NT; ++j)
                acc[i][j] = __builtin_amdgcn_mfma_f32_16x16x32_bf16(a[kt][i], b[kt & 1][j], acc[i][j], 0, 0, 0);
        }
        __builtin_amdgcn_s_setprio(0);
    }

    if (STORE) {
        #pragma unroll
        for (int i = 0; i < MT; ++i) {
            #pragma unroll
            for (int j = 0; j < NT; ++j) {
                const int row = ptb + j * 16 + lr;          // point
                const int col = (otb + i) * 16 + lq * 4;    // output dim (4 contiguous)
                if (OUTF32) {
                    *(f32x4*)((float*)outP + row * sOut + col) = acc[i][j];
                } else {
                    f32x4 v = acc[i][j];
                    if (RELU) {
                        v[0] = fmaxf(v[0], 0.0f); v[1] = fmaxf(v[1], 0.0f);
                        v[2] = fmaxf(v[2], 0.0f); v[3] = fmaxf(v[3], 0.0f);
                    }
                    *(bf16x4*)((short*)outP + row * sOut + col) = cvt4(v);
                }
            }
        }
    }
}

// ---- 32x32x16 batched-preload role-swapped layer (L3, L4) -----------------
//  A: lane -> A[od = otb*32 + (lane&31)][k = kt*16 + (lane>>5)*8 + e]
//  B: lane -> act[pt = ptb + (lane&31)][k = kt*16 + (lane>>5)*8 + e]
//  D (m74/m101): pt = lane&31, od = (r&3) + 8*(r>>2) + 4*(lane>>5)
// PRE: A-frags per batch (2-deep batches issued one ahead, pinned).
template<int K, int OT, int PTS, int MT, int NT, int KTS, int KT0, int PRE,
         bool RELU, bool INIT, bool STORE>
__device__ __forceinline__ void mlp_layer32p(f32x16 (&acc)[MT][NT],
                                             const short* __restrict__ act, const int sIn,
                                             short* __restrict__ outP, const int sOut,
                                             const short* __restrict__ pack,
                                             const float* __restrict__ bias,
                                             const int wave, const int lane) {
    constexpr int PTG = PTS / NT;
    constexpr int OG  = OT / MT;
    constexpr int KT  = K / 16;
    constexpr int NB  = KT / PRE;        // batches (KT % PRE == 0)
    constexpr int AB  = (NB > 1) ? 2 : 1;
    const int og = wave / PTG;
    if (og >= OG) return;
    const int ptb = (wave % PTG) * (NT * 32);
    const int otb = og * MT;
    const int lr = lane & 31, hi = lane >> 5;

    const short* ap = pack + ((otb * KTS + KT0) << 9) + (lane << 3);
    const short* bp = act + (ptb + lr) * sIn + hi * 8;

    if (INIT) {                          // bias first: counted wait, no drain
        #pragma unroll
        for (int i = 0; i < MT; ++i) {
            #pragma unroll
            for (int rg = 0; rg < 4; ++rg) {
                f32x4 bv = *(const f32x4*)(bias + (otb + i) * 32 + rg * 8 + hi * 4);
                #pragma unroll
                for (int j = 0; j < NT; ++j) {
                    acc[i][j][rg * 4 + 0] = bv[0];
                    acc[i][j][rg * 4 + 1] = bv[1];
                    acc[i][j][rg * 4 + 2] = bv[2];
                    acc[i][j][rg * 4 + 3] = bv[3];
                }
            }
        }
    }

    bf16x8 a[AB][PRE][MT], b[2][NT];

#define LOADA(B_, C_)                                                           \
    {   _Pragma("unroll")                                                       \
        for (int t = 0; t < PRE; ++t) {                                         \
            _Pragma("unroll")                                                   \
            for (int i = 0; i < MT; ++i)                                        \
                a[B_][t][i] = *(const bf16x8*)(ap + ((i * KTS + (C_) * PRE + t) << 9)); \
        }                                                                       \
        __builtin_amdgcn_sched_barrier(0); }

    LOADA(0, 0)
    #pragma unroll
    for (int j = 0; j < NT; ++j) b[0][j] = *(const bf16x8*)(bp + j * 32 * sIn);

    #pragma unroll
    for (int bb = 0; bb < NB; ++bb) {
        if (bb + 1 < NB) LOADA((bb + 1) % AB, bb + 1)
        #pragma unroll
        for (int t = 0; t < PRE; ++t) {
            const int kt = bb * PRE + t;
            if (kt + 1 < KT) {
                #pragma unroll
                for (int j = 0; j < NT; ++j)
                    b[(kt + 1) & 1][j] = *(const bf16x8*)(bp + j * 32 * sIn + (kt + 1) * 16);
            }
            __builtin_amdgcn_s_setprio(1);
            #pragma unroll
            for (int i = 0; i < MT; ++i) {
                #pragma unroll
                for (int j = 0; j < NT; ++j)
                    acc[i][j] = __builtin_amdgcn_mfma_f32_32x32x16_bf16(
                        a[bb % AB][t][i], b[kt & 1][j], acc[i][j], 0, 0, 0);
            }
            __builtin_amdgcn_s_setprio(0);
        }
    }
#undef LOADA

    if (STORE) {
        #pragma unroll
        for (int i = 0; i < MT; ++i) {
            #pragma unroll
            for (int j = 0; j < NT; ++j) {
                const int row = ptb + j * 32 + lr;
                #pragma unroll
                for (int rg = 0; rg < 4; ++rg) {
                    f32x4 v;
                    v[0] = acc[i][j][rg * 4 + 0]; v[1] = acc[i][j][rg * 4 + 1];
                    v[2] = acc[i][j][rg * 4 + 2]; v[3] = acc[i][j][rg * 4 + 3];
                    if (RELU) {
                        v[0] = fmaxf(v[0], 0.0f); v[1] = fmaxf(v[1], 0.0f);
                        v[2] = fmaxf(v[2], 0.0f); v[3] = fmaxf(v[3], 0.0f);
                    }
                    *(bf16x4*)(outP + row * sOut + (otb + i) * 32 + rg * 8 + hi * 4) = cvt4(v);
                }
            }
        }
    }
}

__global__ __launch_bounds__(512)
__attribute__((amdgpu_waves_per_eu(4, 4)))
void gridnet_fused(
    const float* __restrict__ pos, const float* __restrict__ grid_pos,
    const float* __restrict__ w1, const float* __restrict__ b1,
    const float* __restrict__ b2, const float* __restrict__ b3,
    const float* __restrict__ b4, const float* __restrict__ b5,
    const short* __restrict__ ws, float* __restrict__ out) {

    // M=64 pts/block. region1: h2 -> h4.  region2: h3a/h3b -> logits(f32).
    // region3: h1 -> h5.  Peak LDS = 33792+33792+9216+512 = 77312 B -> 2 blk/CU.
    __shared__ short region1[64 * 264];
    __shared__ short region2[64 * 264];
    __shared__ short region3[64 * 72];
    __shared__ float posS[128];
    float* logitsS = (float*)region2;    // 64*80*4 = 20480 <= 33792

    const int tid  = threadIdx.x;
    const int wave = tid >> 6;
    const int lane = tid & 63;
    const int m0   = blockIdx.x * 64;

    // ---- early-issue epilogue gathers (depend only on pos); ~10 VGPR ------
    const int pe = tid >> 3;             // point within tile
    const int se = tid & 7;              // sub-lane
    const float pa0 = pos[(m0 + pe) * 2], pa1 = pos[(m0 + pe) * 2 + 1];
    const int txa = (int)(pa0 / PI_F * 1023.0f);
    const int tya = (int)((pa1 + PI_F) / TWO_PI_F * 2047.0f);
    float g0[10];
    #pragma unroll
    for (int i = 0; i < 10; ++i) {
        int f = se + i * 8;
        if (f < 75) {
            int c = f / 25, rr = f % 25, dy = rr / 5, dx = rr % 5;
            g0[i] = grid_pos[((txa + dy) * 2052 + (tya + dx)) * 3 + c];
        } else g0[i] = 0.0f;
    }

    if (tid < 128) posS[tid] = pos[m0 * 2 + tid];
    __syncthreads();

    // ---- layer 1 (2 -> 64), VALU; h1 stored [pt][dim] stride 72 ----
    #pragma unroll
    for (int r = 0; r < 8; ++r) {
        int idx = tid + r * 512;          // 64 pts x 64 dims
        int m = idx >> 6, n = idx & 63;
        float v = fmaf(posS[m * 2 + 0], w1[n], fmaf(posS[m * 2 + 1], w1[64 + n], b1[n]));
        region3[m * 72 + n] = f2bf(fmaxf(v, 0.0f));
    }
    __syncthreads();

    {   // L2: 64 -> 256. PTS=4, NT=4 (PTG=1), MT=2 (OG=8). A preload 16 VGPR.
        f32x4 acc[2][4];
        mlp_layer< 64, 16, 4, 2, 4,  2, 0, true, false, true, true>(
            acc, region3, 72, region1, 264, ws + P2_OFF, b2, wave, lane);
    }
    __syncthreads();

    {   // L3/L4 halves; PTG=1 on 32-shape (NT=2): each weight frag read by
        // ONE wave; its B spans all 64 pts. OG=8, MT=1.
        f32x16 acc4[1][2];
        {   // L3a: h2 -> h3a (od 0..255). PRE=4 (A dbuf 32 VGPR).
            f32x16 acc[1][2];
            mlp_layer32p<256, 8, 2, 1, 2, 16, 0, 4, true, true, true>(
                acc, region1, 264, region2, 264, ws + P3_OFF, b3, wave, lane);
        }
        __syncthreads();
        // L4 part 1: k = 0..255 (h3a), bias-init, no store. PRE=4.
        mlp_layer32p<256, 8, 2, 1, 2, 32, 0, 4, true, true, false>(
            acc4, region2, 264, region1, 264, ws + P4_OFF, b4, wave, lane);
        __syncthreads();
        {   // L3b: h2 -> h3b (od 256..511); PRE=2 (acc3+acc4 live, ~120 VGPR)
            f32x16 acc[1][2];
            mlp_layer32p<256, 8, 2, 1, 2, 16, 0, 2, true, true, true>(
                acc, region1, 264, region2, 264, ws + P3_OFF + 65536, b3 + 256,
                wave, lane);
        }
        __syncthreads();
        // L4 part 2: k = 256..511 (weight k-tiles 16..31), store h4. PRE=4.
        mlp_layer32p<256, 8, 2, 1, 2, 32, 16, 4, true, false, true>(
            acc4, region2, 264, region1, 264, ws + P4_OFF, b4, wave, lane);
    }
    __syncthreads();

    {   // L5: 256 -> 64. PTS=4, NT=2 (PTG=2), MT=1 (OG=4). A preload 32 VGPR.
        f32x4 acc[1][2];
        mlp_layer<256,  4, 4, 1, 2,  8, 0, true, false, true, true>(
            acc, region1, 264, region3, 72, ws + P5_OFF, b5, wave, lane);
    }
    __syncthreads();

    {   // L6: 64 -> 80 logits (f32). PTS=4, NT=4 (PTG=1), MT=1, OG=5.
        f32x4 acc[1][4];
        mlp_layer< 64,  5, 4, 1, 4,  2, 0, false, true, true, true>(
            acc, region3, 72, logitsS, 80, ws + P6_OFF,
            (const float*)(ws + B6_OFF), wave, lane);
    }
    __syncthreads();

    // ---- epilogue: softmax(75) + preloaded gather + sigmoid ----
    {
        const float* lrow = logitsS + pe * 80;
        float lv[10];
        float mx = -1e30f;
        #pragma unroll
        for (int i = 0; i < 10; ++i) {
            int f = se + i * 8;
            float v = (f < 75) ? lrow[f] : -1e30f;
            lv[i] = v;
            mx = fmaxf(mx, v);
        }
        mx = fmaxf(mx, __shfl_xor(mx, 1, 8));
        mx = fmaxf(mx, __shfl_xor(mx, 2, 8));
        mx = fmaxf(mx, __shfl_xor(mx, 4, 8));

        float den = 0.0f, x0 = 0.0f, x1 = 0.0f, x2 = 0.0f;
        #pragma unroll
        for (int i = 0; i < 10; ++i) {
            int f = se + i * 8;
            if (f < 75) {
                float e = __expf(lv[i] - mx);
                den += e;
                int c = f / 25;
                if      (c == 0) x0 += e * g0[i];
                else if (c == 1) x1 += e * g0[i];
                else             x2 += e * g0[i];
            }
        }
        #pragma unroll
        for (int mask = 1; mask < 8; mask <<= 1) {
            den += __shfl_xor(den, mask, 8);
            x0  += __shfl_xor(x0,  mask, 8);
            x1  += __shfl_xor(x1,  mask, 8);
            x2  += __shfl_xor(x2,  mask, 8);
        }
        if (se < 3) {
            float xv = (se == 0) ? x0 : (se == 1 ? x1 : x2);
            xv /= den;
            float sig = 1.0f / (1.0f + __expf(-xv));
            out[(m0 + pe) * 3 + se] = (sig > 0.1f) ? sig * 255.0f : 0.0f;
        }
    }
}

extern "C" void kernel_launch(void* const* d_in, const int* in_sizes, int n_in,
                              void* d_out, int out_size, void* d_ws, size_t ws_size,
                              hipStream_t stream) {
    const float* pos      = (const float*)d_in[0];
    const float* grid_pos = (const float*)d_in[1];
    const float* w1 = (const float*)d_in[2];
    const float* b1 = (const float*)d_in[3];
    const float* w2 = (const float*)d_in[4];
    const float* b2 = (const float*)d_in[5];
    const float* w3 = (const float*)d_in[6];
    const float* b3 = (const float*)d_in[7];
    const float* w4 = (const float*)d_in[8];
    const float* b4 = (const float*)d_in[9];
    const float* w5 = (const float*)d_in[10];
    const float* b5 = (const float*)d_in[11];
    const float* w6 = (const float*)d_in[12];
    const float* b6 = (const float*)d_in[13];
    short* ws = (short*)d_ws;
    float* out = (float*)d_out;

    prep_weights<<<(PREP_TOTAL + 255) / 256, 256, 0, stream>>>(w2, w3, w4, w5, w6, b6, ws);
    gridnet_fused<<<262144 / 64, 512, 0, stream>>>(pos, grid_pos, w1, b1, b2, b3, b4, b5, ws, out);
}